// Round 1
// baseline (172.649 us; speedup 1.0000x reference)
//
#include <hip/hip_runtime.h>
#include <stdint.h>

#define DIMC 256
#define RTOT 1024
#define NE 64
#define NSLOT 1024
#define RCN 8      // r-chunks (grid.x)
#define RCW 128    // r-columns per chunk
#define TILE 32    // max slots per pass (2 MFMA m-tiles)
#define XSTR 264   // padded LDS row stride for A-operand (bf16 elems)
#define NT 16      // 16-tile weight stream: tiles 0..7 = W1, 8..15 = W2

typedef short bfrag __attribute__((ext_vector_type(8)));
typedef float f32x4 __attribute__((ext_vector_type(4)));

// counted vmcnt + raw barrier: keep the global_load_lds pipeline in flight
// across barriers (a plain __syncthreads() would emit vmcnt(0) and drain it).
#define VMCNT(N) asm volatile("s_waitcnt vmcnt(" #N ")" ::: "memory")
#define LGKM0_BAR()                                          \
  do {                                                       \
    asm volatile("s_waitcnt lgkmcnt(0)" ::: "memory");       \
    __builtin_amdgcn_s_barrier();                            \
  } while (0)

static __device__ __forceinline__ unsigned short f2bf(float f) {
  unsigned u = __float_as_uint(f);  // RNE
  return (unsigned short)((u + 0x7FFFu + ((u >> 16) & 1u)) >> 16);
}

static __device__ __forceinline__ bfrag pack8(const float* f) {
  union { unsigned short u[8]; bfrag v; } r;
#pragma unroll
  for (int i = 0; i < 8; ++i) r.u[i] = f2bf(f[i]);
  return r.v;
}

// async global->LDS, 16B per lane. LDS dest must be linear: base + lane*16.
static __device__ __forceinline__ void gload16(const float* g, float* l) {
  __builtin_amdgcn_global_load_lds(
      (const __attribute__((address_space(1))) void*)g,
      (__attribute__((address_space(3))) void*)l, 16, 0, 0);
}

// ---------------- fused bucketing + 2-layer expert MLP via MFMA -------------
// grid: (8 r-chunks, 64 experts), 512 threads = 8 waves, 2 blocks/CU.
// Weight streaming: 16 uniform 16KB fp32 tiles per pass
//   tiles 0..7   : W1 chunk  [32 d][128 r]      (K-steps of layer 1)
//   tiles 8..15  : W2 chunk  [32 r][128 dout]   ((rt,dh) = ((tt-8)>>1, tt&1))
// staged with global_load_lds dwordx4 into a 3-tile ring, 2 tiles ahead,
// counted vmcnt(4) so 32KB/block stays in flight continuously.
// B-fragments read from the LDS tile (8x b32, 4-way conflict) + bf16 pack.
// A-operand (x, then parked h) lives in bf16 LDS X[32][264].
// C/D: col=lane&15, row=(lane>>4)*4+reg.
__global__ __launch_bounds__(512, 4) void mlp_kernel(
    const float* __restrict__ slots, const float* __restrict__ w1,
    const float* __restrict__ b1, const float* __restrict__ w2,
    const float* __restrict__ b2, const int* __restrict__ indices,
    float* __restrict__ out) {
  const int rc = blockIdx.x;   // 0..7
  const int e  = blockIdx.y;   // 0..63
  const int t  = threadIdx.x;
  const int l  = t & 63;       // lane
  const int w  = t >> 6;       // wave 0..7
  const int ln = l & 15;       // fragment n/m index
  const int kg = l >> 4;       // k-group 0..3
  const int rbase = rc * RCW;

  __shared__ __align__(16) float WT[3][4096];              // 48 KB tile ring
  __shared__ __align__(16) unsigned short X[TILE * XSTR];  // 16.5 KB A-operand
  __shared__ int blist[NSLOT];
  __shared__ int sid[TILE];
  __shared__ int bn_s;

  // ---- in-block bucketing (replaces the separate bucket kernel) ----
  if (t == 0) bn_s = 0;
  __syncthreads();
  {
    int i0 = indices[t] & (NE - 1);
    int i1 = indices[t + 512] & (NE - 1);
    if (i0 == e) { int p = atomicAdd(&bn_s, 1); blist[p] = t; }
    if (i1 == e) { int p = atomicAdd(&bn_s, 1); blist[p] = t + 512; }
  }
  __syncthreads();
  const int n = bn_s;
  if (n == 0) return;

  const float* w1e = w1 + (size_t)e * DIMC * RTOT + rbase;                 // [d][r]
  const float* w2e = w2 + (size_t)e * RTOT * DIMC + (size_t)rbase * DIMC;  // [r][dout]
  const int   c    = w * 16 + ln;            // wave-local column 0..127
  const float b1v  = b1[e * RTOT + rbase + c];

  // stage tile tt of the 16-tile weight stream into buf (2x 16B/thread)
  auto STAGE = [&](int tt, float* buf) {
    if (tt < 8) {
      const float* g = w1e + (size_t)(tt * 32 + (t >> 5)) * RTOT + (t & 31) * 4;
      gload16(g, buf + t * 4);
      gload16(g + (size_t)16 * RTOT, buf + 2048 + t * 4);
    } else {
      const int rt = (tt - 8) >> 1, dh = tt & 1;
      const float* g =
          w2e + (size_t)(rt * 32 + (t >> 5)) * DIMC + dh * 128 + (t & 31) * 4;
      gload16(g, buf + t * 4);
      gload16(g + 16 * DIMC, buf + 2048 + t * 4);
    }
  };

  for (int s0 = 0; s0 < n; s0 += TILE) {
    const int m = (n - s0 < TILE) ? (n - s0) : TILE;

    LGKM0_BAR();  // epilogue of previous pass done reading sid/X
    if (t < TILE) sid[t] = (t < m) ? blist[s0 + t] : 0;
    LGKM0_BAR();  // sid visible

    // ---- stage x tile: fp32 global -> bf16 LDS [slot][d]; zero pad rows
#pragma unroll
    for (int i = t; i < TILE * 64; i += 512) {
      int s = i >> 6, d4 = (i & 63) * 4;
      float4 v = make_float4(0.f, 0.f, 0.f, 0.f);
      if (s < m) v = ((const float4*)slots)[(size_t)sid[s] * 64 + (i & 63)];
      union { unsigned short u[4]; uint2 q; } p;
      p.u[0] = f2bf(v.x); p.u[1] = f2bf(v.y);
      p.u[2] = f2bf(v.z); p.u[3] = f2bf(v.w);
      *(uint2*)&X[s * XSTR + d4] = p.q;
    }

    f32x4 acc1[2];
    acc1[0] = (f32x4)(0.f); acc1[1] = (f32x4)(0.f);
    f32x4 acc2[2][2];
#pragma unroll
    for (int mt = 0; mt < 2; ++mt)
#pragma unroll
      for (int dh = 0; dh < 2; ++dh) acc2[mt][dh] = (f32x4)(0.f);

    // ---- prologue: 2 tiles in flight
    STAGE(0, WT[0]);
    STAGE(1, WT[1]);

#pragma unroll
    for (int tt = 0; tt < NT; ++tt) {
      if (tt + 2 < NT) STAGE(tt + 2, WT[(tt + 2) % 3]);

      if (tt == 8) {
        // park h = relu(acc1 + b1) into X[m][r_local]; all waves finished
        // reading x at tt=7's trailing barrier. Visible after barrier below.
#pragma unroll
        for (int mt = 0; mt < 2; ++mt)
#pragma unroll
          for (int reg = 0; reg < 4; ++reg) {
            float h = fmaxf(acc1[mt][reg] + b1v, 0.f);
            X[(mt * 16 + kg * 4 + reg) * XSTR + c] = f2bf(h);
          }
      }

      // tile tt complete (per-wave), 2 tiles still in flight
      if (tt < NT - 2)       VMCNT(4);
      else if (tt == NT - 2) VMCNT(2);
      else                   VMCNT(0);
      LGKM0_BAR();  // all waves' portions of tile tt landed; X writes visible

      // ---- compute tile tt
      {
        const float* buf = WT[tt % 3];
        float f[8];
#pragma unroll
        for (int j = 0; j < 8; ++j) f[j] = buf[(kg * 8 + j) * RCW + c];
        bfrag b = pack8(f);
        if (tt < 8) {  // layer 1, K-step tt
          bfrag a0 = *(const bfrag*)&X[ln * XSTR + tt * 32 + kg * 8];
          bfrag a1 = *(const bfrag*)&X[(16 + ln) * XSTR + tt * 32 + kg * 8];
          acc1[0] = __builtin_amdgcn_mfma_f32_16x16x32_bf16(a0, b, acc1[0], 0, 0, 0);
          acc1[1] = __builtin_amdgcn_mfma_f32_16x16x32_bf16(a1, b, acc1[1], 0, 0, 0);
        } else {       // layer 2, r-step rt, dout-half dh
          const int rt = (tt - 8) >> 1, dh = tt & 1;
          bfrag a0 = *(const bfrag*)&X[ln * XSTR + rt * 32 + kg * 8];
          bfrag a1 = *(const bfrag*)&X[(16 + ln) * XSTR + rt * 32 + kg * 8];
          acc2[0][dh] = __builtin_amdgcn_mfma_f32_16x16x32_bf16(a0, b, acc2[0][dh], 0, 0, 0);
          acc2[1][dh] = __builtin_amdgcn_mfma_f32_16x16x32_bf16(a1, b, acc2[1][dh], 0, 0, 0);
        }
      }

      LGKM0_BAR();  // all waves done reading tile tt -> its buffer reusable
    }

    // ---- epilogue: out[sid[row]][col] += acc (+ b2 once via rc==0)
#pragma unroll
    for (int dh = 0; dh < 2; ++dh) {
      const int col = dh * 128 + c;
      const float b2v = (rc == 0) ? b2[e * DIMC + col] : 0.f;
#pragma unroll
      for (int mt = 0; mt < 2; ++mt)
#pragma unroll
        for (int reg = 0; reg < 4; ++reg) {
          const int row = mt * 16 + kg * 4 + reg;
          if (row < m)
            atomicAdd(&out[(size_t)sid[row] * DIMC + col],
                      acc2[mt][dh][reg] + b2v);
        }
    }
  }
}

extern "C" void kernel_launch(void* const* d_in, const int* in_sizes, int n_in,
                              void* d_out, int out_size, void* d_ws, size_t ws_size,
                              hipStream_t stream) {
  const float* slots   = (const float*)d_in[0];
  const float* w1      = (const float*)d_in[1];
  const float* b1      = (const float*)d_in[2];
  const float* w2      = (const float*)d_in[3];
  const float* b2      = (const float*)d_in[4];
  const int*   indices = (const int*)d_in[5];
  float* out = (float*)d_out;

  (void)d_ws; (void)ws_size;

  hipMemsetAsync(d_out, 0, (size_t)out_size * sizeof(float), stream);
  mlp_kernel<<<dim3(RCN, NE), 512, 0, stream>>>(slots, w1, b1, w2, b2,
                                                indices, out);
}

// Round 2
// 170.394 us; speedup vs baseline: 1.0132x; 1.0132x over previous
//
#include <hip/hip_runtime.h>
#include <stdint.h>

#define DIMC 256
#define RTOT 1024
#define NE 64
#define NSLOT 1024
#define RCN 8      // r-chunks (grid.y now)
#define RCW 128    // r-columns per chunk
#define TILE 32    // max slots per pass (2 MFMA m-tiles)
#define XSTR 264   // padded LDS row stride for A-operand (bf16 elems)
#define NT 16      // 16-tile weight stream: tiles 0..7 = W1, 8..15 = W2

typedef short bfrag __attribute__((ext_vector_type(8)));
typedef float f32x4 __attribute__((ext_vector_type(4)));

// counted vmcnt + raw barrier: keep the global_load_lds pipeline in flight
// across barriers (a plain __syncthreads() would emit vmcnt(0) and drain it).
#define VMCNT(N) asm volatile("s_waitcnt vmcnt(" #N ")" ::: "memory")
#define LGKM0_BAR()                                          \
  do {                                                       \
    asm volatile("s_waitcnt lgkmcnt(0)" ::: "memory");       \
    __builtin_amdgcn_s_barrier();                            \
  } while (0)

static __device__ __forceinline__ unsigned short f2bf(float f) {
  unsigned u = __float_as_uint(f);  // RNE
  return (unsigned short)((u + 0x7FFFu + ((u >> 16) & 1u)) >> 16);
}

static __device__ __forceinline__ bfrag pack8(const float* f) {
  union { unsigned short u[8]; bfrag v; } r;
#pragma unroll
  for (int i = 0; i < 8; ++i) r.u[i] = f2bf(f[i]);
  return r.v;
}

// async global->LDS, 16B per lane. LDS dest must be linear: base + lane*16.
static __device__ __forceinline__ void gload16(const float* g, float* l) {
  __builtin_amdgcn_global_load_lds(
      (const __attribute__((address_space(1))) void*)g,
      (__attribute__((address_space(3))) void*)l, 16, 0, 0);
}

// ---------------- fused bucketing + 2-layer expert MLP via MFMA -------------
// grid: dim3(NE, RCN) -- NOTE ORDER. linear bid = e + 64*rc, so bid%8 = e%8:
// all 8 rc-chunk blocks of expert e are co-resident on ONE XCD, streaming
// complementary 512B column-chunks of the SAME w1/w2 rows in lockstep. Their
// merged request stream is sequential full 4KB rows per expert at the XCD's
// L2/MALL -> DRAM-page-friendly (vs rc%8 scatter = 512B @ 4KB stride per XCD).
// Also makes the 8-way out[] atomicAdd contention XCD-local.
//
// Weight streaming: 16 uniform 16KB fp32 tiles per pass
//   tiles 0..7   : W1 chunk  [32 d][128 r]      (K-steps of layer 1)
//   tiles 8..15  : W2 chunk  [32 r][128 dout]   ((rt,dh) = ((tt-8)>>1, tt&1))
// staged with global_load_lds dwordx4 into a 3-tile ring, 2 tiles ahead,
// counted vmcnt(2) + ONE raw barrier per tile (STAGE issued after the
// barrier: at that point all waves have finished reading the buffer being
// overwritten, so the trailing barrier of the old scheme is redundant).
// B-fragments read from the LDS tile (8x b32, 4-way conflict) + bf16 pack.
// A-operand (x, then parked h) lives in bf16 LDS X[32][264].
// C/D: col=lane&15, row=(lane>>4)*4+reg.
__global__ __launch_bounds__(512, 4) void mlp_kernel(
    const float* __restrict__ slots, const float* __restrict__ w1,
    const float* __restrict__ b1, const float* __restrict__ w2,
    const float* __restrict__ b2, const int* __restrict__ indices,
    float* __restrict__ out) {
  const int e  = blockIdx.x;   // 0..63  (fast dim -> XCD id = e%8)
  const int rc = blockIdx.y;   // 0..7
  const int t  = threadIdx.x;
  const int l  = t & 63;       // lane
  const int w  = t >> 6;       // wave 0..7
  const int ln = l & 15;       // fragment n/m index
  const int kg = l >> 4;       // k-group 0..3
  const int rbase = rc * RCW;

  __shared__ __align__(16) float WT[3][4096];              // 48 KB tile ring
  __shared__ __align__(16) unsigned short X[TILE * XSTR];  // 16.5 KB A-operand
  __shared__ unsigned short blist[NSLOT];                  // 2 KB
  __shared__ int sid[TILE];
  __shared__ int bn_s;

  // ---- in-block bucketing ----
  if (t == 0) bn_s = 0;
  __syncthreads();
  {
    int i0 = indices[t] & (NE - 1);
    int i1 = indices[t + 512] & (NE - 1);
    if (i0 == e) { int p = atomicAdd(&bn_s, 1); blist[p] = (unsigned short)t; }
    if (i1 == e) { int p = atomicAdd(&bn_s, 1); blist[p] = (unsigned short)(t + 512); }
  }
  __syncthreads();
  const int n = bn_s;
  if (n == 0) return;

  const float* w1e = w1 + (size_t)e * DIMC * RTOT + rbase;                 // [d][r]
  const float* w2e = w2 + (size_t)e * RTOT * DIMC + (size_t)rbase * DIMC;  // [r][dout]
  const int   c    = w * 16 + ln;            // wave-local column 0..127
  const float b1v  = b1[e * RTOT + rbase + c];

  // stage tile tt of the 16-tile weight stream into buf (2x 16B/thread)
  auto STAGE = [&](int tt, float* buf) {
    if (tt < 8) {
      const float* g = w1e + (size_t)(tt * 32 + (t >> 5)) * RTOT + (t & 31) * 4;
      gload16(g, buf + t * 4);
      gload16(g + (size_t)16 * RTOT, buf + 2048 + t * 4);
    } else {
      const int rt = (tt - 8) >> 1, dh = tt & 1;
      const float* g =
          w2e + (size_t)(rt * 32 + (t >> 5)) * DIMC + dh * 128 + (t & 31) * 4;
      gload16(g, buf + t * 4);
      gload16(g + 16 * DIMC, buf + 2048 + t * 4);
    }
  };

  for (int s0 = 0; s0 < n; s0 += TILE) {
    const int m = (n - s0 < TILE) ? (n - s0) : TILE;

    LGKM0_BAR();  // previous pass fully done (epilogue reads of sid, X reads)
    if (t < TILE) sid[t] = (t < m) ? (int)blist[s0 + t] : 0;
    LGKM0_BAR();  // sid visible

    // ---- stage x tile: fp32 global -> bf16 LDS [slot][d]; zero pad rows
#pragma unroll
    for (int i = t; i < TILE * 64; i += 512) {
      int s = i >> 6, d4 = (i & 63) * 4;
      float4 v = make_float4(0.f, 0.f, 0.f, 0.f);
      if (s < m) v = ((const float4*)slots)[(size_t)sid[s] * 64 + (i & 63)];
      union { unsigned short u[4]; uint2 q; } p;
      p.u[0] = f2bf(v.x); p.u[1] = f2bf(v.y);
      p.u[2] = f2bf(v.z); p.u[3] = f2bf(v.w);
      *(uint2*)&X[s * XSTR + d4] = p.q;
    }

    f32x4 acc1[2];
    acc1[0] = (f32x4)(0.f); acc1[1] = (f32x4)(0.f);
    f32x4 acc2[2][2];
#pragma unroll
    for (int mt = 0; mt < 2; ++mt)
#pragma unroll
      for (int dh = 0; dh < 2; ++dh) acc2[mt][dh] = (f32x4)(0.f);

    // ---- prologue: 2 tiles in flight
    STAGE(0, WT[0]);
    STAGE(1, WT[1]);

#pragma unroll
    for (int tt = 0; tt < NT; ++tt) {
      // tile tt complete (FIFO vmcnt: waits x-loads + older tiles too)
      if (tt < NT - 1) VMCNT(2);
      else             VMCNT(0);
      LGKM0_BAR();  // all waves: tile tt landed, compute tt-1 done, X visible

      if (tt == 8) {
        // park h = relu(acc1 + b1) into X[m][r_local]. Safe: every wave is
        // past tile 7 > tile 3, so nobody still reads X d-cols [0,128).
#pragma unroll
        for (int mt = 0; mt < 2; ++mt)
#pragma unroll
          for (int reg = 0; reg < 4; ++reg) {
            float h = fmaxf(acc1[mt][reg] + b1v, 0.f);
            X[(mt * 16 + kg * 4 + reg) * XSTR + c] = f2bf(h);
          }
        LGKM0_BAR();  // parked h visible to all waves
      }

      // refill the ring: buffer (tt+2)%3 == (tt-1)%3, whose readers all
      // passed the barrier above.
      if (tt + 2 < NT) STAGE(tt + 2, WT[(tt + 2) % 3]);

      // ---- compute tile tt
      {
        const float* buf = WT[tt % 3];
        float f[8];
#pragma unroll
        for (int j = 0; j < 8; ++j) f[j] = buf[(kg * 8 + j) * RCW + c];
        bfrag b = pack8(f);
        if (tt < 8) {  // layer 1, K-step tt
          bfrag a0 = *(const bfrag*)&X[ln * XSTR + tt * 32 + kg * 8];
          bfrag a1 = *(const bfrag*)&X[(16 + ln) * XSTR + tt * 32 + kg * 8];
          acc1[0] = __builtin_amdgcn_mfma_f32_16x16x32_bf16(a0, b, acc1[0], 0, 0, 0);
          acc1[1] = __builtin_amdgcn_mfma_f32_16x16x32_bf16(a1, b, acc1[1], 0, 0, 0);
        } else {       // layer 2, r-step rt, dout-half dh
          const int rt = (tt - 8) >> 1, dh = tt & 1;
          bfrag a0 = *(const bfrag*)&X[ln * XSTR + rt * 32 + kg * 8];
          bfrag a1 = *(const bfrag*)&X[(16 + ln) * XSTR + rt * 32 + kg * 8];
          acc2[0][dh] = __builtin_amdgcn_mfma_f32_16x16x32_bf16(a0, b, acc2[0][dh], 0, 0, 0);
          acc2[1][dh] = __builtin_amdgcn_mfma_f32_16x16x32_bf16(a1, b, acc2[1][dh], 0, 0, 0);
        }
      }
    }

    // ---- epilogue: out[sid[row]][col] += acc (+ b2 once via rc==0)
#pragma unroll
    for (int dh = 0; dh < 2; ++dh) {
      const int col = dh * 128 + c;
      const float b2v = (rc == 0) ? b2[e * DIMC + col] : 0.f;
#pragma unroll
      for (int mt = 0; mt < 2; ++mt)
#pragma unroll
        for (int reg = 0; reg < 4; ++reg) {
          const int row = mt * 16 + kg * 4 + reg;
          if (row < m)
            atomicAdd(&out[(size_t)sid[row] * DIMC + col],
                      acc2[mt][dh][reg] + b2v);
        }
    }
  }
}

extern "C" void kernel_launch(void* const* d_in, const int* in_sizes, int n_in,
                              void* d_out, int out_size, void* d_ws, size_t ws_size,
                              hipStream_t stream) {
  const float* slots   = (const float*)d_in[0];
  const float* w1      = (const float*)d_in[1];
  const float* b1      = (const float*)d_in[2];
  const float* w2      = (const float*)d_in[3];
  const float* b2      = (const float*)d_in[4];
  const int*   indices = (const int*)d_in[5];
  float* out = (float*)d_out;

  (void)d_ws; (void)ws_size;

  hipMemsetAsync(d_out, 0, (size_t)out_size * sizeof(float), stream);
  // grid order (NE, RCN): bid = e + 64*rc -> all rc-blocks of expert e on
  // the same XCD (bid%8 = e%8).
  mlp_kernel<<<dim3(NE, RCN), 512, 0, stream>>>(slots, w1, b1, w2, b2,
                                                indices, out);
}